// Round 11
// baseline (244.018 us; speedup 1.0000x reference)
//
#include <hip/hip_runtime.h>
#include <hip/hip_fp16.h>

#define EPS 1e-6f

constexpr int N_ = 8;
constexpr int H_ = 720;
constexpr int W_ = 1280;
constexpr int HW = H_ * W_;
constexpr int NPIX = N_ * HW;        // 7,372,800

// Tiling for the privatized splat (R8/R9-verified: 71.5 us splat).
// Confirmed model (R4-R9): LDS ds_add_u64 serializes per LANE at ~1.3-1.5
// cyc/lane-RMW; 2 blocks/CU (79,872 B window) keeps the DS pipe ~90% fed.
// R11 = R10 with the compile fix: ROCm has no atomicAdd(__half2*); the
// rare out-of-halo fallback (~0.4% of corners) uses a u32 CAS loop doing
// a packed-f16 add instead. fb plane is 4 B/px x2^10 -> memset 59->29.5 MB
// and gather's non-ws read side is one uint4 per quad. All sums (ws, fb,
// eps) live in the x2^10 domain; the ratio divides scaled sums directly.
constexpr int TH = 72;               // tile rows   (720 = 10*72, exact)
constexpr int TW = 64;               // tile cols   (1280 = 20*64, exact)
constexpr int R_ = 16;               // halo = 2 sigma of the sigma=8 flow
constexpr int LH = TH + 2 * R_;      // 104
constexpr int LW = TW + 2 * R_;      // 96
constexpr int LSZ = LH * LW;         // 9984 positions
constexpr int TILES_H = H_ / TH;     // 10
constexpr int TILES_W = W_ / TW;     // 20
constexpr int TILES_PER_IMG = TILES_H * TILES_W;        // 200
constexpr size_t WS_PER_IMG = (size_t)TILES_PER_IMG * LSZ * 4; // ~8 MiB (u32 cells)

// Fixed-point LDS pack {img_q26:32 | one_q26:32} (R6-R9 verified).
#define QSCALE 67108864.0f           // 2^26
// q26 int -> f16-stored value (true * 2^10): multiply by 2^-16.
#define QI16   (1.0f / 65536.0f)
// stored -> true
#define SINV   (1.0f / 1024.0f)
// eps in the x2^10 domain
#define EPSS   (EPS * 1024.0f)

__device__ __forceinline__ unsigned pack_cell(unsigned long long v) {
    float im = (float)(unsigned)(v >> 32) * QI16;          // true*2^10
    float on = (float)(unsigned)(v & 0xffffffffull) * QI16;
    unsigned hi = (unsigned)__half_as_ushort(__float2half(im));
    unsigned ho = (unsigned)__half_as_ushort(__float2half(on));
    return hi | (ho << 16);          // low = img, high = one
}

__device__ __forceinline__ float h2f_lo(unsigned u) {
    return __half2float(__ushort_as_half((unsigned short)(u & 0xffff)));
}
__device__ __forceinline__ float h2f_hi(unsigned u) {
    return __half2float(__ushort_as_half((unsigned short)(u >> 16)));
}

__device__ __forceinline__ unsigned pack2f(float a, float b) {
    unsigned lo = (unsigned)__half_as_ushort(__float2half(a));
    unsigned hi = (unsigned)__half_as_ushort(__float2half(b));
    return lo | (hi << 16);
}

// Packed-f16 add into a u32 cell via CAS. Used ONLY on the rare 2-sigma
// tail (~0.4% of splat corners, scattered addresses -> ~no contention).
__device__ __forceinline__ void atomic_h2_add(unsigned* p, float a, float b) {
    unsigned old = __hip_atomic_load(p, __ATOMIC_RELAXED,
                                     __HIP_MEMORY_SCOPE_AGENT);
    unsigned assumed;
    do {
        assumed = old;
        float ca = h2f_lo(assumed) + a;
        float cb = h2f_hi(assumed) + b;
        old = atomicCAS(p, assumed, pack2f(ca, cb));
    } while (old != assumed);
}

// Native f32 atomic add for the no-ws fallback path.
__device__ __forceinline__ void atomic_fadd(float* p, float v) {
    unsafeAtomicAdd(p, v);
}

// ---------------------------------------------------------------------------
// Phase A: per-tile privatized splat. One block = one 72x64 source tile.
// LDS: one u64 plane {img_q26|one_q26} for the 104x96 halo'd window
// (79,872 B -> 2 blocks/CU). 4 x ds_add_u64 per pixel. Out-of-halo
// (2-sigma tail) -> one packed-f16 CAS add into the fb plane (x2^10).
// ---------------------------------------------------------------------------
__global__ __launch_bounds__(512) void splat_tiled_kernel(
        const float* __restrict__ img,
        const float* __restrict__ counts,
        const float* __restrict__ flo,
        unsigned* __restrict__ ws,       // ni * 200 * LSZ packed-h2 cells
        unsigned* __restrict__ fb,       // NPIX fallback h2 cells (zeroed)
        int n0) {
    __shared__ __align__(16) unsigned long long s_acc[LSZ];   // 79,872 B

    int bt = blockIdx.x;                 // chunk-local tile id
    int tc = bt % TILES_W;
    int t2 = bt / TILES_W;
    int tr = t2 % TILES_H;
    int n  = n0 + t2 / TILES_H;
    int row0 = tr * TH;
    int col0 = tc * TW;
    int tid = threadIdx.x;

    // zero LDS (vectorized, conflict-free): 4992 float4
    {
        float4 z = make_float4(0.f, 0.f, 0.f, 0.f);
        float4* z0 = (float4*)s_acc;
        for (int i = tid; i < LSZ / 2; i += 512) z0[i] = z;
    }
    __syncthreads();

    int nbase = n * HW;
    int fbase_n = n * 2 * HW;

    // TH*TW = 4608 = 9 * 512: exactly 9 iterations, no tail; TW=64 -> bit ops.
    for (int p = tid; p < TH * TW; p += 512) {
        int r = p >> 6;
        int c = p & 63;
        int h = row0 + r;
        int w = col0 + c;
        int idx = nbase + h * W_ + w;

        float iv = img[idx];
        float cv = counts[idx];
        int fo = fbase_n + h * W_ + w;
        float y = flo[fo];                 // channel 0 shifts W axis
        float x = flo[fo + HW];            // channel 1 shifts H axis

        float x1 = floorf(x);
        float y1 = floorf(y);
        float fx = x - x1;
        float fy = y - y1;
        float gx = 1.0f - fx;
        float gy = 1.0f - fy;
        float ex1 = __expf(-fx * fx);
        float ex2 = __expf(-gx * gx);
        float ey1 = __expf(-fy * fy);
        float ey2 = __expf(-gy * gy);

        float s = (ex1 + ex2) * (ey1 + ey2);
        float inv = cv / s;

        int ix1 = (int)x1 + h;
        int iy1 = (int)y1 + w;

        int ixr[2] = {ix1, ix1 + 1};
        int iyc[2] = {iy1, iy1 + 1};
        float wx[2] = {ex1, ex2};
        float wy[2] = {ey1, ey2};

        #pragma unroll
        for (int a = 0; a < 2; ++a) {
            #pragma unroll
            for (int b = 0; b < 2; ++b) {
                float ww = wx[a] * wy[b] * inv;
                float wi = iv * ww;
                int lh = ixr[a] - row0 + R_;
                int lw = iyc[b] - col0 + R_;
                if ((unsigned)lh < (unsigned)LH && (unsigned)lw < (unsigned)LW) {
                    unsigned qi = (unsigned)(wi * QSCALE + 0.5f);
                    unsigned qw = (unsigned)(ww * QSCALE + 0.5f);
                    atomicAdd(&s_acc[lh * LW + lw],
                              ((unsigned long long)qi << 32) |
                               (unsigned long long)qw);      // ds_add_u64
                } else if ((unsigned)ixr[a] < (unsigned)H_ &&
                           (unsigned)iyc[b] < (unsigned)W_) {
                    // rare 2-sigma tail: packed-f16 CAS add (x2^10)
                    atomic_h2_add(&fb[nbase + ixr[a] * W_ + iyc[b]],
                                  wi * 1024.0f, ww * 1024.0f);
                }
            }
        }
    }
    __syncthreads();

    // private, coalesced dump: decode q26 -> packed f16 pair per cell,
    // 4 cells (one uint4) per store.
    uint4* wsb = (uint4*)(ws + (size_t)bt * LSZ);
    for (int i = tid; i < LSZ / 4; i += 512) {
        uint4 o4;
        o4.x = pack_cell(s_acc[4 * i]);
        o4.y = pack_cell(s_acc[4 * i + 1]);
        o4.z = pack_cell(s_acc[4 * i + 2]);
        o4.w = pack_cell(s_acc[4 * i + 3]);
        wsb[i] = o4;
    }
}

// ---------------------------------------------------------------------------
// Phase B: gather, 4 pixels per thread. Tile-boundary thresholds (R_=16,
// TW-R_=48, TW=64) are multiples of 4, so an aligned quad shares one
// (tr,tc) tile set; each tile contribution is ONE uint4 load. The
// fallback plane is one more uint4 per quad. All sums stay in the x2^10
// domain; the ratio divides scaled sums directly (eps also scaled).
// ---------------------------------------------------------------------------
__global__ __launch_bounds__(256) void gather_kernel(
        const unsigned* __restrict__ ws,
        const unsigned* __restrict__ fb,
        float* __restrict__ out0,
        float* __restrict__ out1,
        int n0, int npix_chunk) {
    int pidx = (blockIdx.x * 256 + threadIdx.x) * 4;
    if (pidx >= npix_chunk) return;
    int w0 = pidx % W_;               // multiple of 4
    int t = pidx / W_;
    int h = t % H_;                   // uniform across each wave (256 | W_)
    int nl = t / H_;                  // chunk-local image index

    int gidx = (n0 + nl) * HW + h * W_ + w0;

    // fallback plane (x2^10 domain)
    const uint4 f = *(const uint4*)(fb + gidx);
    float4 si, so;
    si.x = h2f_lo(f.x); so.x = h2f_hi(f.x);
    si.y = h2f_lo(f.y); so.y = h2f_hi(f.y);
    si.z = h2f_lo(f.z); so.z = h2f_hi(f.z);
    si.w = h2f_lo(f.w); so.w = h2f_hi(f.w);

    int tr_lo = (h >= R_) ? (h - R_) / TH : 0;
    int tr_hi = (h + R_) / TH; if (tr_hi > TILES_H - 1) tr_hi = TILES_H - 1;
    int tc_lo = (w0 >= R_) ? (w0 - R_) / TW : 0;
    int tc_hi = (w0 + 3 + R_) / TW; if (tc_hi > TILES_W - 1) tc_hi = TILES_W - 1;

    for (int tr = tr_lo; tr <= tr_hi; ++tr) {
        int lh = h - tr * TH + R_;
        for (int tc = tc_lo; tc <= tc_hi; ++tc) {
            int lw0 = w0 - tc * TW + R_;          // multiple of 4
            const uint4 a = *(const uint4*)(ws
                + ((size_t)((nl * TILES_H + tr) * TILES_W + tc)) * LSZ
                + (size_t)(lh * LW + lw0));
            si.x += h2f_lo(a.x); so.x += h2f_hi(a.x);
            si.y += h2f_lo(a.y); so.y += h2f_hi(a.y);
            si.z += h2f_lo(a.z); so.z += h2f_hi(a.z);
            si.w += h2f_lo(a.w); so.w += h2f_hi(a.w);
        }
    }
    float4 r;
    r.x = si.x / (so.x + EPSS);
    r.y = si.y / (so.y + EPSS);
    r.z = si.z / (so.z + EPSS);
    r.w = si.w / (so.w + EPSS);
    float4 o1;
    o1.x = so.x * SINV;
    o1.y = so.y * SINV;
    o1.z = so.z * SINV;
    o1.w = so.w * SINV;
    *(float4*)(out0 + gidx) = r;
    *(float4*)(out1 + gidx) = o1;
}

// ---------------------------------------------------------------------------
// Fallback path (ws too small): direct-atomic version into out planes.
// ---------------------------------------------------------------------------
__global__ void splat_atomic_kernel(const float* __restrict__ img,
                                    const float* __restrict__ counts,
                                    const float* __restrict__ flo,
                                    float* __restrict__ acc_img,
                                    float* __restrict__ acc_one) {
    int idx = blockIdx.x * blockDim.x + threadIdx.x;
    if (idx >= NPIX) return;
    int w = idx % W_;
    int t = idx / W_;
    int h = t % H_;
    int n = t / H_;

    float iv = img[idx];
    float cv = counts[idx];
    int fbase = ((n * 2) * H_ + h) * W_ + w;
    float y = flo[fbase];
    float x = flo[fbase + HW];

    float x1 = floorf(x);
    float y1 = floorf(y);
    float fx = x - x1, fy = y - y1;
    float gx = 1.0f - fx, gy = 1.0f - fy;
    float ex1 = __expf(-fx * fx), ex2 = __expf(-gx * gx);
    float ey1 = __expf(-fy * fy), ey2 = __expf(-gy * gy);
    float s = (ex1 + ex2) * (ey1 + ey2);
    float inv = cv / s;

    int ix1 = (int)x1 + h, ix2 = ix1 + 1;
    int iy1 = (int)y1 + w, iy2 = iy1 + 1;
    int nbase = n * HW;
    if ((unsigned)ix1 < (unsigned)H_ && (unsigned)iy1 < (unsigned)W_) {
        int o = nbase + ix1 * W_ + iy1; float ww = ex1 * ey1 * inv;
        atomic_fadd(acc_img + o, iv * ww); atomic_fadd(acc_one + o, ww);
    }
    if ((unsigned)ix1 < (unsigned)H_ && (unsigned)iy2 < (unsigned)W_) {
        int o = nbase + ix1 * W_ + iy2; float ww = ex1 * ey2 * inv;
        atomic_fadd(acc_img + o, iv * ww); atomic_fadd(acc_one + o, ww);
    }
    if ((unsigned)ix2 < (unsigned)H_ && (unsigned)iy1 < (unsigned)W_) {
        int o = nbase + ix2 * W_ + iy1; float ww = ex2 * ey1 * inv;
        atomic_fadd(acc_img + o, iv * ww); atomic_fadd(acc_one + o, ww);
    }
    if ((unsigned)ix2 < (unsigned)H_ && (unsigned)iy2 < (unsigned)W_) {
        int o = nbase + ix2 * W_ + iy2; float ww = ex2 * ey2 * inv;
        atomic_fadd(acc_img + o, iv * ww); atomic_fadd(acc_one + o, ww);
    }
}

__global__ void finalize_kernel(float* __restrict__ out0,
                                const float* __restrict__ out1) {
    int idx = blockIdx.x * blockDim.x + threadIdx.x;
    if (idx >= NPIX) return;
    out0[idx] = out0[idx] / (out1[idx] + EPS);
}

extern "C" void kernel_launch(void* const* d_in, const int* in_sizes, int n_in,
                              void* d_out, int out_size, void* d_ws, size_t ws_size,
                              hipStream_t stream) {
    const float* img    = (const float*)d_in[0];
    const float* counts = (const float*)d_in[1];
    const float* flo    = (const float*)d_in[2];

    float* out0 = (float*)d_out;
    float* out1 = out0 + NPIX;

    const size_t fb_bytes = (size_t)NPIX * 4;   // packed h2 per pixel, 29.5 MB

    if (ws_size >= WS_PER_IMG + fb_bytes + 16) {
        // tiled path: tiles at the front of ws, fallback plane at the back
        size_t fb_off = (ws_size - fb_bytes) & ~(size_t)15;
        unsigned* ws = (unsigned*)d_ws;
        unsigned* fb = (unsigned*)((char*)d_ws + fb_off);

        int ipc = (int)(fb_off / WS_PER_IMG);
        if (ipc > N_) ipc = N_;

        // zero only the fallback plane; gather writes every output pixel.
        hipMemsetAsync(fb, 0, fb_bytes, stream);

        for (int n0 = 0; n0 < N_; n0 += ipc) {
            int ni = (n0 + ipc <= N_) ? ipc : (N_ - n0);
            splat_tiled_kernel<<<ni * TILES_PER_IMG, 512, 0, stream>>>(
                img, counts, flo, ws, fb, n0);
            int npix_chunk = ni * HW;
            gather_kernel<<<(npix_chunk / 4 + 255) / 256, 256, 0, stream>>>(
                ws, fb, out0, out1, n0, npix_chunk);
        }
    } else {
        hipMemsetAsync(d_out, 0, (size_t)2 * NPIX * sizeof(float), stream);
        const int threads = 256;
        const int blocks = (NPIX + threads - 1) / threads;
        splat_atomic_kernel<<<blocks, threads, 0, stream>>>(img, counts, flo,
                                                            out0, out1);
        finalize_kernel<<<blocks, threads, 0, stream>>>(out0, out1);
    }
}

// Round 12
// 202.035 us; speedup vs baseline: 1.2078x; 1.2078x over previous
//
#include <hip/hip_runtime.h>
#include <hip/hip_fp16.h>
#include <type_traits>

#define EPS 1e-6f

constexpr int N_ = 8;
constexpr int H_ = 720;
constexpr int W_ = 1280;
constexpr int HW = H_ * W_;
constexpr int NPIX = N_ * HW;        // 7,372,800

// Tiling for the privatized splat (R8/R9-verified: 71.5 us splat).
// Confirmed model (R4-R11): LDS ds_add_u64 serializes per LANE at ~1.3-1.5
// cyc/lane-RMW; 2 blocks/CU (79,872 B window) keeps the DS pipe ~90% fed.
// The splat tolerates unlimited FIRE-AND-FORGET atomic traffic but not
// blocking round-trips: R11's CAS-loop tail cost +39 us. R12 restores a
// non-blocking tail via native packed-f16 global atomic
// (global_atomic_pk_add_f16), SFINAE-gated: if HIP exposes
// unsafeAtomicAdd(__half2*,__half2) use it (no return -> no stall),
// else fall back to the CAS loop (compiles everywhere).
constexpr int TH = 72;               // tile rows   (720 = 10*72, exact)
constexpr int TW = 64;               // tile cols   (1280 = 20*64, exact)
constexpr int R_ = 16;               // halo = 2 sigma of the sigma=8 flow
constexpr int LH = TH + 2 * R_;      // 104
constexpr int LW = TW + 2 * R_;      // 96
constexpr int LSZ = LH * LW;         // 9984 positions
constexpr int TILES_H = H_ / TH;     // 10
constexpr int TILES_W = W_ / TW;     // 20
constexpr int TILES_PER_IMG = TILES_H * TILES_W;        // 200
constexpr size_t WS_PER_IMG = (size_t)TILES_PER_IMG * LSZ * 4; // ~8 MiB (u32 cells)

// Fixed-point LDS pack {img_q26:32 | one_q26:32} (R6-R9 verified).
#define QSCALE 67108864.0f           // 2^26
// q26 int -> f16-stored value (true * 2^10): multiply by 2^-16.
#define QI16   (1.0f / 65536.0f)
// stored -> true
#define SINV   (1.0f / 1024.0f)
// eps in the x2^10 domain
#define EPSS   (EPS * 1024.0f)

__device__ __forceinline__ unsigned pack_cell(unsigned long long v) {
    float im = (float)(unsigned)(v >> 32) * QI16;          // true*2^10
    float on = (float)(unsigned)(v & 0xffffffffull) * QI16;
    unsigned hi = (unsigned)__half_as_ushort(__float2half(im));
    unsigned ho = (unsigned)__half_as_ushort(__float2half(on));
    return hi | (ho << 16);          // low = img, high = one
}

__device__ __forceinline__ float h2f_lo(unsigned u) {
    return __half2float(__ushort_as_half((unsigned short)(u & 0xffff)));
}
__device__ __forceinline__ float h2f_hi(unsigned u) {
    return __half2float(__ushort_as_half((unsigned short)(u >> 16)));
}

__device__ __forceinline__ unsigned pack2f(float a, float b) {
    unsigned lo = (unsigned)__half_as_ushort(__float2half(a));
    unsigned hi = (unsigned)__half_as_ushort(__float2half(b));
    return lo | (hi << 16);
}

// --- SFINAE probe: does unsafeAtomicAdd have a __half2 overload? ----------
template <typename T, typename = void>
struct has_unsafe_h2 : std::false_type {};
template <typename T>
struct has_unsafe_h2<T, std::void_t<decltype(
    unsafeAtomicAdd(std::declval<T*>(), std::declval<T>()))>>
    : std::true_type {};

// Packed-f16 add into a u32 cell. Native pk_add_f16 (fire-and-forget) if
// available; CAS loop otherwise. Tail-only (~0.4% of splat corners).
__device__ __forceinline__ void atomic_h2_add(unsigned* p, float a, float b) {
    if constexpr (has_unsafe_h2<__half2>::value) {
        unsafeAtomicAdd((__half2*)p, __floats2half2_rn(a, b));
    } else {
        unsigned old = __hip_atomic_load(p, __ATOMIC_RELAXED,
                                         __HIP_MEMORY_SCOPE_AGENT);
        unsigned assumed;
        do {
            assumed = old;
            float ca = h2f_lo(assumed) + a;
            float cb = h2f_hi(assumed) + b;
            old = atomicCAS(p, assumed, pack2f(ca, cb));
        } while (old != assumed);
    }
}

// Native f32 atomic add for the no-ws fallback path.
__device__ __forceinline__ void atomic_fadd(float* p, float v) {
    unsafeAtomicAdd(p, v);
}

// ---------------------------------------------------------------------------
// Phase A: per-tile privatized splat. One block = one 72x64 source tile.
// LDS: one u64 plane {img_q26|one_q26} for the 104x96 halo'd window
// (79,872 B -> 2 blocks/CU). 4 x ds_add_u64 per pixel. Out-of-halo
// (2-sigma tail) -> one packed-f16 atomic into the fb plane (x2^10).
// ---------------------------------------------------------------------------
__global__ __launch_bounds__(512) void splat_tiled_kernel(
        const float* __restrict__ img,
        const float* __restrict__ counts,
        const float* __restrict__ flo,
        unsigned* __restrict__ ws,       // ni * 200 * LSZ packed-h2 cells
        unsigned* __restrict__ fb,       // NPIX fallback h2 cells (zeroed)
        int n0) {
    __shared__ __align__(16) unsigned long long s_acc[LSZ];   // 79,872 B

    int bt = blockIdx.x;                 // chunk-local tile id
    int tc = bt % TILES_W;
    int t2 = bt / TILES_W;
    int tr = t2 % TILES_H;
    int n  = n0 + t2 / TILES_H;
    int row0 = tr * TH;
    int col0 = tc * TW;
    int tid = threadIdx.x;

    // zero LDS (vectorized, conflict-free): 4992 float4
    {
        float4 z = make_float4(0.f, 0.f, 0.f, 0.f);
        float4* z0 = (float4*)s_acc;
        for (int i = tid; i < LSZ / 2; i += 512) z0[i] = z;
    }
    __syncthreads();

    int nbase = n * HW;
    int fbase_n = n * 2 * HW;

    // TH*TW = 4608 = 9 * 512: exactly 9 iterations, no tail; TW=64 -> bit ops.
    for (int p = tid; p < TH * TW; p += 512) {
        int r = p >> 6;
        int c = p & 63;
        int h = row0 + r;
        int w = col0 + c;
        int idx = nbase + h * W_ + w;

        float iv = img[idx];
        float cv = counts[idx];
        int fo = fbase_n + h * W_ + w;
        float y = flo[fo];                 // channel 0 shifts W axis
        float x = flo[fo + HW];            // channel 1 shifts H axis

        float x1 = floorf(x);
        float y1 = floorf(y);
        float fx = x - x1;
        float fy = y - y1;
        float gx = 1.0f - fx;
        float gy = 1.0f - fy;
        float ex1 = __expf(-fx * fx);
        float ex2 = __expf(-gx * gx);
        float ey1 = __expf(-fy * fy);
        float ey2 = __expf(-gy * gy);

        float s = (ex1 + ex2) * (ey1 + ey2);
        float inv = cv / s;

        int ix1 = (int)x1 + h;
        int iy1 = (int)y1 + w;

        int ixr[2] = {ix1, ix1 + 1};
        int iyc[2] = {iy1, iy1 + 1};
        float wx[2] = {ex1, ex2};
        float wy[2] = {ey1, ey2};

        #pragma unroll
        for (int a = 0; a < 2; ++a) {
            #pragma unroll
            for (int b = 0; b < 2; ++b) {
                float ww = wx[a] * wy[b] * inv;
                float wi = iv * ww;
                int lh = ixr[a] - row0 + R_;
                int lw = iyc[b] - col0 + R_;
                if ((unsigned)lh < (unsigned)LH && (unsigned)lw < (unsigned)LW) {
                    unsigned qi = (unsigned)(wi * QSCALE + 0.5f);
                    unsigned qw = (unsigned)(ww * QSCALE + 0.5f);
                    atomicAdd(&s_acc[lh * LW + lw],
                              ((unsigned long long)qi << 32) |
                               (unsigned long long)qw);      // ds_add_u64
                } else if ((unsigned)ixr[a] < (unsigned)H_ &&
                           (unsigned)iyc[b] < (unsigned)W_) {
                    // rare 2-sigma tail: packed-f16 atomic add (x2^10)
                    atomic_h2_add(&fb[nbase + ixr[a] * W_ + iyc[b]],
                                  wi * 1024.0f, ww * 1024.0f);
                }
            }
        }
    }
    __syncthreads();

    // private, coalesced dump: decode q26 -> packed f16 pair per cell,
    // 4 cells (one uint4) per store.
    uint4* wsb = (uint4*)(ws + (size_t)bt * LSZ);
    for (int i = tid; i < LSZ / 4; i += 512) {
        uint4 o4;
        o4.x = pack_cell(s_acc[4 * i]);
        o4.y = pack_cell(s_acc[4 * i + 1]);
        o4.z = pack_cell(s_acc[4 * i + 2]);
        o4.w = pack_cell(s_acc[4 * i + 3]);
        wsb[i] = o4;
    }
}

// ---------------------------------------------------------------------------
// Phase B: gather, 4 pixels per thread. Tile-boundary thresholds (R_=16,
// TW-R_=48, TW=64) are multiples of 4, so an aligned quad shares one
// (tr,tc) tile set; each tile contribution is ONE uint4 load. The
// fallback plane is one more uint4 per quad. All sums stay in the x2^10
// domain; the ratio divides scaled sums directly (eps also scaled).
// ---------------------------------------------------------------------------
__global__ __launch_bounds__(256) void gather_kernel(
        const unsigned* __restrict__ ws,
        const unsigned* __restrict__ fb,
        float* __restrict__ out0,
        float* __restrict__ out1,
        int n0, int npix_chunk) {
    int pidx = (blockIdx.x * 256 + threadIdx.x) * 4;
    if (pidx >= npix_chunk) return;
    int w0 = pidx % W_;               // multiple of 4
    int t = pidx / W_;
    int h = t % H_;                   // uniform across each wave (256 | W_)
    int nl = t / H_;                  // chunk-local image index

    int gidx = (n0 + nl) * HW + h * W_ + w0;

    // fallback plane (x2^10 domain)
    const uint4 f = *(const uint4*)(fb + gidx);
    float4 si, so;
    si.x = h2f_lo(f.x); so.x = h2f_hi(f.x);
    si.y = h2f_lo(f.y); so.y = h2f_hi(f.y);
    si.z = h2f_lo(f.z); so.z = h2f_hi(f.z);
    si.w = h2f_lo(f.w); so.w = h2f_hi(f.w);

    int tr_lo = (h >= R_) ? (h - R_) / TH : 0;
    int tr_hi = (h + R_) / TH; if (tr_hi > TILES_H - 1) tr_hi = TILES_H - 1;
    int tc_lo = (w0 >= R_) ? (w0 - R_) / TW : 0;
    int tc_hi = (w0 + 3 + R_) / TW; if (tc_hi > TILES_W - 1) tc_hi = TILES_W - 1;

    for (int tr = tr_lo; tr <= tr_hi; ++tr) {
        int lh = h - tr * TH + R_;
        for (int tc = tc_lo; tc <= tc_hi; ++tc) {
            int lw0 = w0 - tc * TW + R_;          // multiple of 4
            const uint4 a = *(const uint4*)(ws
                + ((size_t)((nl * TILES_H + tr) * TILES_W + tc)) * LSZ
                + (size_t)(lh * LW + lw0));
            si.x += h2f_lo(a.x); so.x += h2f_hi(a.x);
            si.y += h2f_lo(a.y); so.y += h2f_hi(a.y);
            si.z += h2f_lo(a.z); so.z += h2f_hi(a.z);
            si.w += h2f_lo(a.w); so.w += h2f_hi(a.w);
        }
    }
    float4 r;
    r.x = si.x / (so.x + EPSS);
    r.y = si.y / (so.y + EPSS);
    r.z = si.z / (so.z + EPSS);
    r.w = si.w / (so.w + EPSS);
    float4 o1;
    o1.x = so.x * SINV;
    o1.y = so.y * SINV;
    o1.z = so.z * SINV;
    o1.w = so.w * SINV;
    *(float4*)(out0 + gidx) = r;
    *(float4*)(out1 + gidx) = o1;
}

// ---------------------------------------------------------------------------
// Fallback path (ws too small): direct-atomic version into out planes.
// ---------------------------------------------------------------------------
__global__ void splat_atomic_kernel(const float* __restrict__ img,
                                    const float* __restrict__ counts,
                                    const float* __restrict__ flo,
                                    float* __restrict__ acc_img,
                                    float* __restrict__ acc_one) {
    int idx = blockIdx.x * blockDim.x + threadIdx.x;
    if (idx >= NPIX) return;
    int w = idx % W_;
    int t = idx / W_;
    int h = t % H_;
    int n = t / H_;

    float iv = img[idx];
    float cv = counts[idx];
    int fbase = ((n * 2) * H_ + h) * W_ + w;
    float y = flo[fbase];
    float x = flo[fbase + HW];

    float x1 = floorf(x);
    float y1 = floorf(y);
    float fx = x - x1, fy = y - y1;
    float gx = 1.0f - fx, gy = 1.0f - fy;
    float ex1 = __expf(-fx * fx), ex2 = __expf(-gx * gx);
    float ey1 = __expf(-fy * fy), ey2 = __expf(-gy * gy);
    float s = (ex1 + ex2) * (ey1 + ey2);
    float inv = cv / s;

    int ix1 = (int)x1 + h, ix2 = ix1 + 1;
    int iy1 = (int)y1 + w, iy2 = iy1 + 1;
    int nbase = n * HW;
    if ((unsigned)ix1 < (unsigned)H_ && (unsigned)iy1 < (unsigned)W_) {
        int o = nbase + ix1 * W_ + iy1; float ww = ex1 * ey1 * inv;
        atomic_fadd(acc_img + o, iv * ww); atomic_fadd(acc_one + o, ww);
    }
    if ((unsigned)ix1 < (unsigned)H_ && (unsigned)iy2 < (unsigned)W_) {
        int o = nbase + ix1 * W_ + iy2; float ww = ex1 * ey2 * inv;
        atomic_fadd(acc_img + o, iv * ww); atomic_fadd(acc_one + o, ww);
    }
    if ((unsigned)ix2 < (unsigned)H_ && (unsigned)iy1 < (unsigned)W_) {
        int o = nbase + ix2 * W_ + iy1; float ww = ex2 * ey1 * inv;
        atomic_fadd(acc_img + o, iv * ww); atomic_fadd(acc_one + o, ww);
    }
    if ((unsigned)ix2 < (unsigned)H_ && (unsigned)iy2 < (unsigned)W_) {
        int o = nbase + ix2 * W_ + iy2; float ww = ex2 * ey2 * inv;
        atomic_fadd(acc_img + o, iv * ww); atomic_fadd(acc_one + o, ww);
    }
}

__global__ void finalize_kernel(float* __restrict__ out0,
                                const float* __restrict__ out1) {
    int idx = blockIdx.x * blockDim.x + threadIdx.x;
    if (idx >= NPIX) return;
    out0[idx] = out0[idx] / (out1[idx] + EPS);
}

extern "C" void kernel_launch(void* const* d_in, const int* in_sizes, int n_in,
                              void* d_out, int out_size, void* d_ws, size_t ws_size,
                              hipStream_t stream) {
    const float* img    = (const float*)d_in[0];
    const float* counts = (const float*)d_in[1];
    const float* flo    = (const float*)d_in[2];

    float* out0 = (float*)d_out;
    float* out1 = out0 + NPIX;

    const size_t fb_bytes = (size_t)NPIX * 4;   // packed h2 per pixel, 29.5 MB

    if (ws_size >= WS_PER_IMG + fb_bytes + 16) {
        // tiled path: tiles at the front of ws, fallback plane at the back
        size_t fb_off = (ws_size - fb_bytes) & ~(size_t)15;
        unsigned* ws = (unsigned*)d_ws;
        unsigned* fb = (unsigned*)((char*)d_ws + fb_off);

        int ipc = (int)(fb_off / WS_PER_IMG);
        if (ipc > N_) ipc = N_;

        // zero only the fallback plane; gather writes every output pixel.
        (void)hipMemsetAsync(fb, 0, fb_bytes, stream);

        for (int n0 = 0; n0 < N_; n0 += ipc) {
            int ni = (n0 + ipc <= N_) ? ipc : (N_ - n0);
            splat_tiled_kernel<<<ni * TILES_PER_IMG, 512, 0, stream>>>(
                img, counts, flo, ws, fb, n0);
            int npix_chunk = ni * HW;
            gather_kernel<<<(npix_chunk / 4 + 255) / 256, 256, 0, stream>>>(
                ws, fb, out0, out1, n0, npix_chunk);
        }
    } else {
        (void)hipMemsetAsync(d_out, 0, (size_t)2 * NPIX * sizeof(float), stream);
        const int threads = 256;
        const int blocks = (NPIX + threads - 1) / threads;
        splat_atomic_kernel<<<blocks, threads, 0, stream>>>(img, counts, flo,
                                                            out0, out1);
        finalize_kernel<<<blocks, threads, 0, stream>>>(out0, out1);
    }
}